// Round 5
// baseline (400.306 us; speedup 1.0000x reference)
//
#include <hip/hip_runtime.h>
#include <hip/hip_bf16.h>

#define N_NODES 100000
#define N_EDGES 1600000
#define IN_DIM 64
#define HID 32
#define OUT_DIM 40

#define NBUK 196     // buckets: dst >> 9 (512 nodes each)
#define BCAP 9216    // per-bucket capacity (mean 8163, sigma ~90)
#define BIN_TILE 8192

__device__ __forceinline__ float bf2f(unsigned short u) {
    return __uint_as_float(((unsigned int)u) << 16);
}
__device__ __forceinline__ unsigned short f2bf(float f) {
    unsigned int u = __float_as_uint(f);
    u = (u + 0x7fffu + ((u >> 16) & 1u)) >> 16;  // RNE
    return (unsigned short)u;
}

// Detect whether edge_index is stored as int64 (odd dwords all zero) or int32.
__global__ void detect_i64(const int* __restrict__ p, int* __restrict__ flagp) {
    __shared__ int s_any;
    if (threadIdx.x == 0) s_any = 0;
    __syncthreads();
    int any = 0;
    for (int i = threadIdx.x; i < 2048; i += blockDim.x) any |= p[2 * i + 1];
    if (any) atomicOr(&s_any, 1);
    __syncthreads();
    if (threadIdx.x == 0) *flagp = (s_any == 0) ? 1 : 0;  // 1 => int64 layout
}

__device__ __forceinline__ int load_idx(const void* ei, int i64, long long pos) {
    if (i64) return (int)((const long long*)ei)[pos];
    return ((const int*)ei)[pos];
}

// Pass 1: bin edges by dst>>9 into per-bucket regions, coalesced writes.
// Packed value: (src << 9) | (dst & 511)  -- 26 bits.
__global__ __launch_bounds__(1024) void bin_kernel(const void* __restrict__ ei,
                                                   const int* __restrict__ flagp,
                                                   int* __restrict__ cnt,
                                                   int* __restrict__ binned) {
    __shared__ int lcount[NBUK];
    __shared__ int lscan[NBUK + 1];
    __shared__ int lcur[NBUK];
    __shared__ int lbase[NBUK];
    __shared__ int stage[BIN_TILE];
    const int t = threadIdx.x;
    for (int i = t; i < NBUK; i += 1024) lcount[i] = 0;
    __syncthreads();

    const long long e0 = (long long)blockIdx.x * BIN_TILE;
    const int i64 = *flagp;
    int vv[8], bb[8];
#pragma unroll
    for (int k = 0; k < 8; ++k) {
        const long long e = e0 + (long long)k * 1024 + t;
        if (e < N_EDGES) {
            const int s = load_idx(ei, i64, e);
            const int d = load_idx(ei, i64, N_EDGES + e);
            bb[k] = d >> 9;
            vv[k] = (s << 9) | (d & 511);
            atomicAdd(&lcount[bb[k]], 1);
        } else {
            bb[k] = -1;
        }
    }
    __syncthreads();
    if (t == 0) {
        int acc = 0;
        for (int i = 0; i < NBUK; ++i) {
            lscan[i] = acc;
            acc += lcount[i];
        }
        lscan[NBUK] = acc;
    }
    __syncthreads();
    for (int i = t; i < NBUK; i += 1024) {
        const int c = lcount[i];
        lbase[i] = i * BCAP + (c > 0 ? atomicAdd(&cnt[i], c) : 0);
        lcur[i] = lscan[i];
    }
    __syncthreads();
#pragma unroll
    for (int k = 0; k < 8; ++k) {
        if (bb[k] >= 0) {
            const int pos = atomicAdd(&lcur[bb[k]], 1);
            stage[pos] = vv[k];
        }
    }
    __syncthreads();
    const int total = lscan[NBUK];
    for (int j = t; j < total; j += 1024) {
        int lo = 0, hi = NBUK;
        while (hi - lo > 1) {
            const int mid = (lo + hi) >> 1;
            if (lscan[mid] <= j) lo = mid;
            else hi = mid;
        }
        binned[lbase[lo] + (j - lscan[lo])] = stage[j];
    }
}

// scan over bucket counts -> per-bucket CSR base; rowstart[N] = E
__global__ __launch_bounds__(256) void bscan_kernel(const int* __restrict__ cnt,
                                                    int* __restrict__ bbase,
                                                    int* __restrict__ rowstart) {
    __shared__ int s[256];
    const int t = threadIdx.x;
    const int v = (t < NBUK) ? cnt[t] : 0;
    s[t] = v;
    __syncthreads();
    for (int off = 1; off < 256; off <<= 1) {
        const int add = (t >= off) ? s[t - off] : 0;
        __syncthreads();
        s[t] += add;
        __syncthreads();
    }
    if (t < NBUK) bbase[t] = s[t] - v;
    if (t == 0) rowstart[N_NODES] = N_EDGES;
}

// Pass 2: per-bucket LDS counting sort -> rowstart + csr (src per slot).
__global__ __launch_bounds__(512) void sort_kernel(const int* __restrict__ cnt,
                                                   const int* __restrict__ bbase,
                                                   const int* __restrict__ binned,
                                                   int* __restrict__ rowstart,
                                                   int* __restrict__ csr) {
    __shared__ int counts[512];
    __shared__ int sc[512];
    const int b = blockIdx.x;
    const int t = threadIdx.x;
    const int n = cnt[b];
    const int base = bbase[b];
    const int* __restrict__ bin = binned + (long long)b * BCAP;
    counts[t] = 0;
    __syncthreads();
    for (int i = t; i < n; i += 512) atomicAdd(&counts[bin[i] & 511], 1);
    __syncthreads();
    const int v = counts[t];
    sc[t] = v;
    __syncthreads();
    for (int off = 1; off < 512; off <<= 1) {
        const int add = (t >= off) ? sc[t - off] : 0;
        __syncthreads();
        sc[t] += add;
        __syncthreads();
    }
    const int excl = sc[t] - v;
    const int node = b * 512 + t;
    if (node < N_NODES) rowstart[node] = base + excl;
    counts[t] = excl;  // reuse as local cursor
    __syncthreads();
    for (int i = t; i < n; i += 512) {
        const int vv = bin[i];
        const int pos = atomicAdd(&counts[vv & 511], 1);
        csr[base + pos] = vv >> 9;
    }
}

// Layer-1 projection: yl(bf16) = x @ Wl, yr(fp32) = x @ Wr
__global__ __launch_bounds__(256) void lin1_kernel(
    const float* __restrict__ x, const float* __restrict__ Wl,
    const float* __restrict__ Wr, unsigned short* __restrict__ yl,
    float* __restrict__ yr) {
    __shared__ float sWl[IN_DIM * HID];
    __shared__ float sWr[IN_DIM * HID];
    __shared__ float sX[64 * IN_DIM];
    const int t = threadIdx.x;
    for (int i = t; i < IN_DIM * HID; i += 256) {
        sWl[i] = Wl[i];
        sWr[i] = Wr[i];
    }
    const long long r0 = (long long)blockIdx.x * 64;
    const int nrows = (int)((N_NODES - r0) < 64 ? (N_NODES - r0) : 64);
    const float4* xv = (const float4*)(x + r0 * IN_DIM);
    float4* sXv = (float4*)sX;
    for (int i = t; i < nrows * 16; i += 256) sXv[i] = xv[i];
    __syncthreads();

    const int c = t & 31;
    const int rbase = (t >> 5) * 8;
    float al[8] = {0, 0, 0, 0, 0, 0, 0, 0};
    float ar[8] = {0, 0, 0, 0, 0, 0, 0, 0};
    for (int k = 0; k < IN_DIM; k += 4) {
        const float wl0 = sWl[(k + 0) * HID + c];
        const float wl1 = sWl[(k + 1) * HID + c];
        const float wl2 = sWl[(k + 2) * HID + c];
        const float wl3 = sWl[(k + 3) * HID + c];
        const float wr0 = sWr[(k + 0) * HID + c];
        const float wr1 = sWr[(k + 1) * HID + c];
        const float wr2 = sWr[(k + 2) * HID + c];
        const float wr3 = sWr[(k + 3) * HID + c];
#pragma unroll
        for (int r = 0; r < 8; ++r) {
            const float4 xv4 = *(const float4*)&sX[(rbase + r) * IN_DIM + k];
            al[r] = fmaf(xv4.x, wl0, al[r]);
            al[r] = fmaf(xv4.y, wl1, al[r]);
            al[r] = fmaf(xv4.z, wl2, al[r]);
            al[r] = fmaf(xv4.w, wl3, al[r]);
            ar[r] = fmaf(xv4.x, wr0, ar[r]);
            ar[r] = fmaf(xv4.y, wr1, ar[r]);
            ar[r] = fmaf(xv4.z, wr2, ar[r]);
            ar[r] = fmaf(xv4.w, wr3, ar[r]);
        }
    }
#pragma unroll
    for (int r = 0; r < 8; ++r) {
        if (rbase + r < nrows) yr[(r0 + rbase + r) * HID + c] = ar[r];
    }
    __syncthreads();
    unsigned short* sB = (unsigned short*)sX;
#pragma unroll
    for (int r = 0; r < 8; ++r) {
        if (rbase + r < nrows) sB[(rbase + r) * HID + c] = f2bf(al[r]);
    }
    __syncthreads();
    uint4* dst = (uint4*)(yl + r0 * HID);
    const uint4* src = (const uint4*)sB;
    for (int i = t; i < nrows * 4; i += 256) dst[i] = src[i];
}

// Edge-parallel accumulate phase shared by both fused gathers.
// Block covers 32 consecutive nodes; acc[32][33] fp32 partial sums in LDS.
__device__ __forceinline__ void edge_accum(const int* __restrict__ csr,
                                           const unsigned short* __restrict__ yl,
                                           const int* srow, float* acc, int t) {
    const int q = t & 7;
    const int estart = srow[0];
    const int eend = srow[32];
    const int nE = eend - estart;
    const int nPair = (nE + 1) >> 1;
    for (int i = t; i < nPair * 8; i += 256) {
        const int e0 = estart + ((i >> 3) << 1);
        const int e1 = e0 + 1;
        const int s0 = csr[e0];
        // binary search: owner node lo of e0 (srow[lo] <= e0 < srow[lo+1])
        int lo = 0, hi = 32;
#pragma unroll
        for (int step = 0; step < 5; ++step) {
            const int mid = (lo + hi) >> 1;
            if (srow[mid] <= e0) lo = mid;
            else hi = mid;
        }
        const ushort4 v0 = *(const ushort4*)(yl + (long long)s0 * HID + q * 4);
        float fx = bf2f(v0.x), fy = bf2f(v0.y), fz = bf2f(v0.z), fw = bf2f(v0.w);
        const bool has1 = (e1 < eend);
        if (has1 && e1 < srow[lo + 1]) {
            // same owner: merge before atomic (common case, deg ~16)
            const int s1 = csr[e1];
            const ushort4 v1 = *(const ushort4*)(yl + (long long)s1 * HID + q * 4);
            fx += bf2f(v1.x);
            fy += bf2f(v1.y);
            fz += bf2f(v1.z);
            fw += bf2f(v1.w);
            float* a = &acc[lo * 33 + q * 4];
            atomicAdd(a + 0, fx);
            atomicAdd(a + 1, fy);
            atomicAdd(a + 2, fz);
            atomicAdd(a + 3, fw);
        } else {
            float* a = &acc[lo * 33 + q * 4];
            atomicAdd(a + 0, fx);
            atomicAdd(a + 1, fy);
            atomicAdd(a + 2, fz);
            atomicAdd(a + 3, fw);
            if (has1) {
                const int s1 = csr[e1];
                const ushort4 v1 =
                    *(const ushort4*)(yl + (long long)s1 * HID + q * 4);
                int lo1 = 0, hi1 = 32;
#pragma unroll
                for (int step = 0; step < 5; ++step) {
                    const int mid = (lo1 + hi1) >> 1;
                    if (srow[mid] <= e1) lo1 = mid;
                    else hi1 = mid;
                }
                float* a1 = &acc[lo1 * 33 + q * 4];
                atomicAdd(a1 + 0, bf2f(v1.x));
                atomicAdd(a1 + 1, bf2f(v1.y));
                atomicAdd(a1 + 2, bf2f(v1.z));
                atomicAdd(a1 + 3, bf2f(v1.w));
            }
        }
    }
}

// Fused: gather-mean(Y1l) + combine(Y1r,b1) -> h1 (LDS) -> y2l/y2r = h1 @ W2
__global__ __launch_bounds__(256) void gather_lin2(
    const int* __restrict__ rowstart, const int* __restrict__ csr,
    const unsigned short* __restrict__ yl, const float* __restrict__ yr,
    const float* __restrict__ b, const float* __restrict__ W2l,
    const float* __restrict__ W2r, unsigned short* __restrict__ y2l,
    float* __restrict__ y2r) {
    __shared__ float acc[32 * 33];
    __shared__ float sW2l[HID * HID];
    __shared__ float sW2r[HID * HID];
    __shared__ int srow[33];
    const int t = threadIdx.x;
    for (int i = t; i < HID * HID; i += 256) {
        sW2l[i] = W2l[i];
        sW2r[i] = W2r[i];
    }
    const int n0 = blockIdx.x * 32;
    if (t < 33) srow[t] = rowstart[n0 + t];
    for (int i = t; i < 32 * 33; i += 256) acc[i] = 0.f;
    __syncthreads();

    edge_accum(csr, yl, srow, acc, t);
    __syncthreads();

    const int ln = t >> 3;
    const int q = t & 7;
    const int node = n0 + ln;
    const int deg = srow[ln + 1] - srow[ln];
    const float inv = 1.0f / fmaxf((float)deg, 1.0f);
    float a0 = acc[ln * 33 + q * 4 + 0];
    float a1 = acc[ln * 33 + q * 4 + 1];
    float a2 = acc[ln * 33 + q * 4 + 2];
    float a3 = acc[ln * 33 + q * 4 + 3];
    const float4 rr = *(const float4*)(yr + (long long)node * HID + q * 4);
    const float4 bb = *(const float4*)(b + q * 4);
    a0 = fmaxf(fmaf(a0, inv, bb.x) + rr.x, 0.f);
    a1 = fmaxf(fmaf(a1, inv, bb.y) + rr.y, 0.f);
    a2 = fmaxf(fmaf(a2, inv, bb.z) + rr.z, 0.f);
    a3 = fmaxf(fmaf(a3, inv, bb.w) + rr.w, 0.f);
    __syncthreads();
    acc[ln * 33 + q * 4 + 0] = a0;
    acc[ln * 33 + q * 4 + 1] = a1;
    acc[ln * 33 + q * 4 + 2] = a2;
    acc[ln * 33 + q * 4 + 3] = a3;
    __syncthreads();
    float l0 = 0, l1 = 0, l2 = 0, l3 = 0, m0 = 0, m1 = 0, m2 = 0, m3 = 0;
#pragma unroll
    for (int k = 0; k < HID; ++k) {
        const float hk = acc[ln * 33 + k];
        const float4 wl = *(const float4*)&sW2l[k * HID + q * 4];
        const float4 wr = *(const float4*)&sW2r[k * HID + q * 4];
        l0 = fmaf(hk, wl.x, l0);
        l1 = fmaf(hk, wl.y, l1);
        l2 = fmaf(hk, wl.z, l2);
        l3 = fmaf(hk, wl.w, l3);
        m0 = fmaf(hk, wr.x, m0);
        m1 = fmaf(hk, wr.y, m1);
        m2 = fmaf(hk, wr.z, m2);
        m3 = fmaf(hk, wr.w, m3);
    }
    *(float4*)(y2r + (long long)node * HID + q * 4) = make_float4(m0, m1, m2, m3);
    ushort4 p;
    p.x = f2bf(l0);
    p.y = f2bf(l1);
    p.z = f2bf(l2);
    p.w = f2bf(l3);
    *(ushort4*)(y2l + (long long)node * HID + q * 4) = p;
}

// Fused: gather-mean(Y2l) + combine(Y2r,b2) -> h2 (LDS) -> out = h2 @ w
__global__ __launch_bounds__(256) void gather_out(
    const int* __restrict__ rowstart, const int* __restrict__ csr,
    const unsigned short* __restrict__ yl, const float* __restrict__ yr,
    const float* __restrict__ b, const float* __restrict__ w,
    float* __restrict__ out) {
    __shared__ float acc[32 * 33];
    __shared__ float sW[HID * OUT_DIM];
    __shared__ int srow[33];
    const int t = threadIdx.x;
    for (int i = t; i < HID * OUT_DIM; i += 256) sW[i] = w[i];
    const int n0 = blockIdx.x * 32;
    if (t < 33) srow[t] = rowstart[n0 + t];
    for (int i = t; i < 32 * 33; i += 256) acc[i] = 0.f;
    __syncthreads();

    edge_accum(csr, yl, srow, acc, t);
    __syncthreads();

    const int ln = t >> 3;
    const int q = t & 7;
    const int node = n0 + ln;
    const int deg = srow[ln + 1] - srow[ln];
    const float inv = 1.0f / fmaxf((float)deg, 1.0f);
    float a0 = acc[ln * 33 + q * 4 + 0];
    float a1 = acc[ln * 33 + q * 4 + 1];
    float a2 = acc[ln * 33 + q * 4 + 2];
    float a3 = acc[ln * 33 + q * 4 + 3];
    const float4 rr = *(const float4*)(yr + (long long)node * HID + q * 4);
    const float4 bb = *(const float4*)(b + q * 4);
    a0 = fmaxf(fmaf(a0, inv, bb.x) + rr.x, 0.f);
    a1 = fmaxf(fmaf(a1, inv, bb.y) + rr.y, 0.f);
    a2 = fmaxf(fmaf(a2, inv, bb.z) + rr.z, 0.f);
    a3 = fmaxf(fmaf(a3, inv, bb.w) + rr.w, 0.f);
    __syncthreads();
    acc[ln * 33 + q * 4 + 0] = a0;
    acc[ln * 33 + q * 4 + 1] = a1;
    acc[ln * 33 + q * 4 + 2] = a2;
    acc[ln * 33 + q * 4 + 3] = a3;
    __syncthreads();
    float o[5] = {0, 0, 0, 0, 0};
#pragma unroll
    for (int k = 0; k < HID; ++k) {
        const float hk = acc[ln * 33 + k];
#pragma unroll
        for (int j = 0; j < 5; ++j)
            o[j] = fmaf(hk, sW[k * OUT_DIM + q + 8 * j], o[j]);
    }
#pragma unroll
    for (int j = 0; j < 5; ++j) out[(long long)node * OUT_DIM + q + 8 * j] = o[j];
}

extern "C" void kernel_launch(void* const* d_in, const int* in_sizes, int n_in,
                              void* d_out, int out_size, void* d_ws,
                              size_t ws_size, hipStream_t stream) {
    const float* x = (const float*)d_in[0];
    const void* ei = d_in[1];
    const float* W1l = (const float*)d_in[2];
    const float* b1 = (const float*)d_in[3];
    const float* W1r = (const float*)d_in[4];
    const float* W2l = (const float*)d_in[5];
    const float* b2 = (const float*)d_in[6];
    const float* W2r = (const float*)d_in[7];
    const float* w = (const float*)d_in[8];
    float* out = (float*)d_out;

    // workspace layout (4-byte units)
    int* ip = (int*)d_ws;
    int* flagp = ip;                        // [64]
    int* cnt = ip + 64;                     // [196] pad to 256
    int* bbase = ip + 320;                  // [196] pad to 256
    int* rowstart = ip + 576;               // [100001] pad 100032
    int* csr = rowstart + 100032;           // [1600000]
    float* Y1r = (float*)(csr + N_EDGES);   // [N*HID] fp32
    float* Y2r = Y1r + (long long)N_NODES * HID;            // [N*HID] fp32
    unsigned short* Y1l = (unsigned short*)(Y2r + (long long)N_NODES * HID);
    unsigned short* Y2l = Y1l + (long long)N_NODES * HID;
    // binned aliases Y2r: dead after sort_kernel, before gather_lin2 writes Y2r
    int* binned = (int*)Y2r;                // [NBUK*BCAP] = 1.81M ints < 3.2M

    hipMemsetAsync(cnt, 0, 256 * sizeof(int), stream);
    detect_i64<<<1, 256, 0, stream>>>((const int*)ei, flagp);

    // ---- build CSR: bucket pass + per-bucket LDS counting sort ----
    bin_kernel<<<(N_EDGES + BIN_TILE - 1) / BIN_TILE, 1024, 0, stream>>>(
        ei, flagp, cnt, binned);
    bscan_kernel<<<1, 256, 0, stream>>>(cnt, bbase, rowstart);
    sort_kernel<<<NBUK, 512, 0, stream>>>(cnt, bbase, binned, rowstart, csr);

    // ---- layer 1 projection ----
    lin1_kernel<<<(N_NODES + 63) / 64, 256, 0, stream>>>(x, W1l, W1r, Y1l, Y1r);

    // ---- fused gather1 + combine + layer-2 projection ----
    gather_lin2<<<N_NODES / 32, 256, 0, stream>>>(rowstart, csr, Y1l, Y1r, b1,
                                                  W2l, W2r, Y2l, Y2r);

    // ---- fused gather2 + combine + output projection ----
    gather_out<<<N_NODES / 32, 256, 0, stream>>>(rowstart, csr, Y2l, Y2r, b2, w,
                                                 out);
}

// Round 6
// 160.076 us; speedup vs baseline: 2.5007x; 2.5007x over previous
//
#include <hip/hip_runtime.h>
#include <hip/hip_bf16.h>

#define N_NODES 100000
#define N_EDGES 1600000
#define IN_DIM 64
#define HID 32
#define OUT_DIM 40

#define NBUK 196     // buckets: dst >> 9 (512 nodes each)
#define BCAP 9216    // per-bucket capacity (mean 8163, sigma ~90)
#define BIN_TILE 8192

__device__ __forceinline__ float bf2f(unsigned short u) {
    return __uint_as_float(((unsigned int)u) << 16);
}
__device__ __forceinline__ unsigned short f2bf(float f) {
    unsigned int u = __float_as_uint(f);
    u = (u + 0x7fffu + ((u >> 16) & 1u)) >> 16;  // RNE
    return (unsigned short)u;
}

// Detect whether edge_index is stored as int64 (odd dwords all zero) or int32.
__global__ void detect_i64(const int* __restrict__ p, int* __restrict__ flagp) {
    __shared__ int s_any;
    if (threadIdx.x == 0) s_any = 0;
    __syncthreads();
    int any = 0;
    for (int i = threadIdx.x; i < 2048; i += blockDim.x) any |= p[2 * i + 1];
    if (any) atomicOr(&s_any, 1);
    __syncthreads();
    if (threadIdx.x == 0) *flagp = (s_any == 0) ? 1 : 0;  // 1 => int64 layout
}

__device__ __forceinline__ int load_idx(const void* ei, int i64, long long pos) {
    if (i64) return (int)((const long long*)ei)[pos];
    return ((const int*)ei)[pos];
}

// Pass 1: bin edges by dst>>9 into per-bucket regions, coalesced writes.
// Packed value: (src << 9) | (dst & 511)  -- 26 bits.
__global__ __launch_bounds__(1024) void bin_kernel(const void* __restrict__ ei,
                                                   const int* __restrict__ flagp,
                                                   int* __restrict__ cnt,
                                                   int* __restrict__ binned) {
    __shared__ int lcount[NBUK];
    __shared__ int lscan[NBUK + 1];
    __shared__ int lcur[NBUK];
    __shared__ int lbase[NBUK];
    __shared__ int stage[BIN_TILE];
    const int t = threadIdx.x;
    for (int i = t; i < NBUK; i += 1024) lcount[i] = 0;
    __syncthreads();

    const long long e0 = (long long)blockIdx.x * BIN_TILE;
    const int i64 = *flagp;
    int vv[8], bb[8];
#pragma unroll
    for (int k = 0; k < 8; ++k) {
        const long long e = e0 + (long long)k * 1024 + t;
        if (e < N_EDGES) {
            const int s = load_idx(ei, i64, e);
            const int d = load_idx(ei, i64, N_EDGES + e);
            bb[k] = d >> 9;
            vv[k] = (s << 9) | (d & 511);
            atomicAdd(&lcount[bb[k]], 1);
        } else {
            bb[k] = -1;
        }
    }
    __syncthreads();
    if (t == 0) {
        int acc = 0;
        for (int i = 0; i < NBUK; ++i) {
            lscan[i] = acc;
            acc += lcount[i];
        }
        lscan[NBUK] = acc;
    }
    __syncthreads();
    for (int i = t; i < NBUK; i += 1024) {
        const int c = lcount[i];
        lbase[i] = i * BCAP + (c > 0 ? atomicAdd(&cnt[i], c) : 0);
        lcur[i] = lscan[i];
    }
    __syncthreads();
#pragma unroll
    for (int k = 0; k < 8; ++k) {
        if (bb[k] >= 0) {
            const int pos = atomicAdd(&lcur[bb[k]], 1);
            stage[pos] = vv[k];
        }
    }
    __syncthreads();
    const int total = lscan[NBUK];
    for (int j = t; j < total; j += 1024) {
        int lo = 0, hi = NBUK;
        while (hi - lo > 1) {
            const int mid = (lo + hi) >> 1;
            if (lscan[mid] <= j) lo = mid;
            else hi = mid;
        }
        binned[lbase[lo] + (j - lscan[lo])] = stage[j];
    }
}

// scan over bucket counts -> per-bucket CSR base; rowstart[N] = E
__global__ __launch_bounds__(256) void bscan_kernel(const int* __restrict__ cnt,
                                                    int* __restrict__ bbase,
                                                    int* __restrict__ rowstart) {
    __shared__ int s[256];
    const int t = threadIdx.x;
    const int v = (t < NBUK) ? cnt[t] : 0;
    s[t] = v;
    __syncthreads();
    for (int off = 1; off < 256; off <<= 1) {
        const int add = (t >= off) ? s[t - off] : 0;
        __syncthreads();
        s[t] += add;
        __syncthreads();
    }
    if (t < NBUK) bbase[t] = s[t] - v;
    if (t == 0) rowstart[N_NODES] = N_EDGES;
}

// Pass 2: per-bucket LDS counting sort -> rowstart + csr (src per slot).
__global__ __launch_bounds__(512) void sort_kernel(const int* __restrict__ cnt,
                                                   const int* __restrict__ bbase,
                                                   const int* __restrict__ binned,
                                                   int* __restrict__ rowstart,
                                                   int* __restrict__ csr) {
    __shared__ int counts[512];
    __shared__ int sc[512];
    const int b = blockIdx.x;
    const int t = threadIdx.x;
    const int n = cnt[b];
    const int base = bbase[b];
    const int* __restrict__ bin = binned + (long long)b * BCAP;
    counts[t] = 0;
    __syncthreads();
    for (int i = t; i < n; i += 512) atomicAdd(&counts[bin[i] & 511], 1);
    __syncthreads();
    const int v = counts[t];
    sc[t] = v;
    __syncthreads();
    for (int off = 1; off < 512; off <<= 1) {
        const int add = (t >= off) ? sc[t - off] : 0;
        __syncthreads();
        sc[t] += add;
        __syncthreads();
    }
    const int excl = sc[t] - v;
    const int node = b * 512 + t;
    if (node < N_NODES) rowstart[node] = base + excl;
    counts[t] = excl;  // reuse as local cursor
    __syncthreads();
    for (int i = t; i < n; i += 512) {
        const int vv = bin[i];
        const int pos = atomicAdd(&counts[vv & 511], 1);
        csr[base + pos] = vv >> 9;
    }
}

// Layer-1 projection: yl(bf16) = x @ Wl, yr(fp32) = x @ Wr
__global__ __launch_bounds__(256) void lin1_kernel(
    const float* __restrict__ x, const float* __restrict__ Wl,
    const float* __restrict__ Wr, unsigned short* __restrict__ yl,
    float* __restrict__ yr) {
    __shared__ float sWl[IN_DIM * HID];
    __shared__ float sWr[IN_DIM * HID];
    __shared__ float sX[64 * IN_DIM];
    const int t = threadIdx.x;
    for (int i = t; i < IN_DIM * HID; i += 256) {
        sWl[i] = Wl[i];
        sWr[i] = Wr[i];
    }
    const long long r0 = (long long)blockIdx.x * 64;
    const int nrows = (int)((N_NODES - r0) < 64 ? (N_NODES - r0) : 64);
    const float4* xv = (const float4*)(x + r0 * IN_DIM);
    float4* sXv = (float4*)sX;
    for (int i = t; i < nrows * 16; i += 256) sXv[i] = xv[i];
    __syncthreads();

    const int c = t & 31;
    const int rbase = (t >> 5) * 8;
    float al[8] = {0, 0, 0, 0, 0, 0, 0, 0};
    float ar[8] = {0, 0, 0, 0, 0, 0, 0, 0};
    for (int k = 0; k < IN_DIM; k += 4) {
        const float wl0 = sWl[(k + 0) * HID + c];
        const float wl1 = sWl[(k + 1) * HID + c];
        const float wl2 = sWl[(k + 2) * HID + c];
        const float wl3 = sWl[(k + 3) * HID + c];
        const float wr0 = sWr[(k + 0) * HID + c];
        const float wr1 = sWr[(k + 1) * HID + c];
        const float wr2 = sWr[(k + 2) * HID + c];
        const float wr3 = sWr[(k + 3) * HID + c];
#pragma unroll
        for (int r = 0; r < 8; ++r) {
            const float4 xv4 = *(const float4*)&sX[(rbase + r) * IN_DIM + k];
            al[r] = fmaf(xv4.x, wl0, al[r]);
            al[r] = fmaf(xv4.y, wl1, al[r]);
            al[r] = fmaf(xv4.z, wl2, al[r]);
            al[r] = fmaf(xv4.w, wl3, al[r]);
            ar[r] = fmaf(xv4.x, wr0, ar[r]);
            ar[r] = fmaf(xv4.y, wr1, ar[r]);
            ar[r] = fmaf(xv4.z, wr2, ar[r]);
            ar[r] = fmaf(xv4.w, wr3, ar[r]);
        }
    }
#pragma unroll
    for (int r = 0; r < 8; ++r) {
        if (rbase + r < nrows) yr[(r0 + rbase + r) * HID + c] = ar[r];
    }
    __syncthreads();
    unsigned short* sB = (unsigned short*)sX;
#pragma unroll
    for (int r = 0; r < 8; ++r) {
        if (rbase + r < nrows) sB[(rbase + r) * HID + c] = f2bf(al[r]);
    }
    __syncthreads();
    uint4* dst = (uint4*)(yl + r0 * HID);
    const uint4* src = (const uint4*)sB;
    for (int i = t; i < nrows * 4; i += 256) dst[i] = src[i];
}

// Gather-mean with 32 lanes/node: 4 edge-slots x 8 col-groups, register
// accumulation, shfl_xor cross-slot reduce. Returns h (combined) in all lanes'
// a0..a3 for cols q*4..q*4+3. Also writes h into sH[g*33 + ...].
__device__ __forceinline__ void gather_node32(
    const int* __restrict__ csr, const unsigned short* __restrict__ yl,
    const float* __restrict__ yr, const float* __restrict__ b, int node,
    int start, int end, int slot, int q, float* sHrow) {
    float ax = 0.f, ay = 0.f, az = 0.f, aw = 0.f;
    int e = start + slot;
    for (; e + 4 < end; e += 8) {
        const int s0 = csr[e];
        const int s1 = csr[e + 4];
        const ushort4 v0 = *(const ushort4*)(yl + (long long)s0 * HID + q * 4);
        const ushort4 v1 = *(const ushort4*)(yl + (long long)s1 * HID + q * 4);
        ax += bf2f(v0.x) + bf2f(v1.x);
        ay += bf2f(v0.y) + bf2f(v1.y);
        az += bf2f(v0.z) + bf2f(v1.z);
        aw += bf2f(v0.w) + bf2f(v1.w);
    }
    if (e < end) {
        const int s0 = csr[e];
        const ushort4 v0 = *(const ushort4*)(yl + (long long)s0 * HID + q * 4);
        ax += bf2f(v0.x);
        ay += bf2f(v0.y);
        az += bf2f(v0.z);
        aw += bf2f(v0.w);
    }
    // fold 4 slots (lanes differing by 8 and 16 within the 32-lane group)
    ax += __shfl_xor(ax, 8, 32);
    ay += __shfl_xor(ay, 8, 32);
    az += __shfl_xor(az, 8, 32);
    aw += __shfl_xor(aw, 8, 32);
    ax += __shfl_xor(ax, 16, 32);
    ay += __shfl_xor(ay, 16, 32);
    az += __shfl_xor(az, 16, 32);
    aw += __shfl_xor(aw, 16, 32);
    const float inv = 1.0f / fmaxf((float)(end - start), 1.0f);
    const float4 rr = *(const float4*)(yr + (long long)node * HID + q * 4);
    const float4 bb = *(const float4*)(b + q * 4);
    if (slot == 0) {
        sHrow[q * 4 + 0] = fmaxf(fmaf(ax, inv, bb.x) + rr.x, 0.f);
        sHrow[q * 4 + 1] = fmaxf(fmaf(ay, inv, bb.y) + rr.y, 0.f);
        sHrow[q * 4 + 2] = fmaxf(fmaf(az, inv, bb.z) + rr.z, 0.f);
        sHrow[q * 4 + 3] = fmaxf(fmaf(aw, inv, bb.w) + rr.w, 0.f);
    }
}

// Fused: gather-mean(Y1l) + combine(Y1r,b1) -> h1 (LDS) -> y2l/y2r = h1 @ W2
__global__ __launch_bounds__(256) void gather_lin2(
    const int* __restrict__ rowstart, const int* __restrict__ csr,
    const unsigned short* __restrict__ yl, const float* __restrict__ yr,
    const float* __restrict__ b, const float* __restrict__ W2l,
    const float* __restrict__ W2r, unsigned short* __restrict__ y2l,
    float* __restrict__ y2r) {
    __shared__ float sH[8 * 33];
    __shared__ float sW2l[HID * HID];
    __shared__ float sW2r[HID * HID];
    __shared__ int srow[9];
    const int t = threadIdx.x;
    for (int i = t; i < HID * HID; i += 256) {
        sW2l[i] = W2l[i];
        sW2r[i] = W2r[i];
    }
    const int n0 = blockIdx.x * 8;
    if (t < 9) srow[t] = rowstart[n0 + t];
    __syncthreads();

    const int g = t >> 5;      // node within block
    const int sub = t & 31;
    const int slot = sub >> 3; // edge slot 0..3
    const int q = sub & 7;     // col group (4 cols)
    const int node = n0 + g;
    gather_node32(csr, yl, yr, b, node, srow[g], srow[g + 1], slot, q,
                  &sH[g * 33]);
    __syncthreads();

    // GEMM: each lane computes one output column (sub) for its node
    float l = 0.f, m = 0.f;
#pragma unroll
    for (int k = 0; k < HID; ++k) {
        const float hk = sH[g * 33 + k];
        l = fmaf(hk, sW2l[k * HID + sub], l);
        m = fmaf(hk, sW2r[k * HID + sub], m);
    }
    y2r[(long long)node * HID + sub] = m;
    y2l[(long long)node * HID + sub] = f2bf(l);
}

// Fused: gather-mean(Y2l) + combine(Y2r,b2) -> h2 (LDS) -> out = h2 @ w
__global__ __launch_bounds__(256) void gather_out(
    const int* __restrict__ rowstart, const int* __restrict__ csr,
    const unsigned short* __restrict__ yl, const float* __restrict__ yr,
    const float* __restrict__ b, const float* __restrict__ w,
    float* __restrict__ out) {
    __shared__ float sH[8 * 33];
    __shared__ float sW[HID * OUT_DIM];
    __shared__ int srow[9];
    const int t = threadIdx.x;
    for (int i = t; i < HID * OUT_DIM; i += 256) sW[i] = w[i];
    const int n0 = blockIdx.x * 8;
    if (t < 9) srow[t] = rowstart[n0 + t];
    __syncthreads();

    const int g = t >> 5;
    const int sub = t & 31;
    const int slot = sub >> 3;
    const int q = sub & 7;
    const int node = n0 + g;
    gather_node32(csr, yl, yr, b, node, srow[g], srow[g + 1], slot, q,
                  &sH[g * 33]);
    __syncthreads();

    // GEMM: lane computes col sub, and (if sub<8) col 32+sub
    float o0 = 0.f, o1 = 0.f;
#pragma unroll
    for (int k = 0; k < HID; ++k) {
        const float hk = sH[g * 33 + k];
        o0 = fmaf(hk, sW[k * OUT_DIM + sub], o0);
        o1 = fmaf(hk, sW[k * OUT_DIM + 32 + (sub & 7)], o1);
    }
    out[(long long)node * OUT_DIM + sub] = o0;
    if (sub < 8) out[(long long)node * OUT_DIM + 32 + sub] = o1;
}

extern "C" void kernel_launch(void* const* d_in, const int* in_sizes, int n_in,
                              void* d_out, int out_size, void* d_ws,
                              size_t ws_size, hipStream_t stream) {
    const float* x = (const float*)d_in[0];
    const void* ei = d_in[1];
    const float* W1l = (const float*)d_in[2];
    const float* b1 = (const float*)d_in[3];
    const float* W1r = (const float*)d_in[4];
    const float* W2l = (const float*)d_in[5];
    const float* b2 = (const float*)d_in[6];
    const float* W2r = (const float*)d_in[7];
    const float* w = (const float*)d_in[8];
    float* out = (float*)d_out;

    // workspace layout (4-byte units)
    int* ip = (int*)d_ws;
    int* flagp = ip;                        // [64]
    int* cnt = ip + 64;                     // [196] pad to 256
    int* bbase = ip + 320;                  // [196] pad to 256
    int* rowstart = ip + 576;               // [100001] pad 100032
    int* csr = rowstart + 100032;           // [1600000]
    float* Y1r = (float*)(csr + N_EDGES);   // [N*HID] fp32
    float* Y2r = Y1r + (long long)N_NODES * HID;            // [N*HID] fp32
    unsigned short* Y1l = (unsigned short*)(Y2r + (long long)N_NODES * HID);
    unsigned short* Y2l = Y1l + (long long)N_NODES * HID;
    // binned aliases Y2r: dead after sort_kernel, before gather_lin2 writes Y2r
    int* binned = (int*)Y2r;                // [NBUK*BCAP] = 1.81M ints < 3.2M

    hipMemsetAsync(cnt, 0, 256 * sizeof(int), stream);
    detect_i64<<<1, 256, 0, stream>>>((const int*)ei, flagp);

    // ---- build CSR: bucket pass + per-bucket LDS counting sort ----
    bin_kernel<<<(N_EDGES + BIN_TILE - 1) / BIN_TILE, 1024, 0, stream>>>(
        ei, flagp, cnt, binned);
    bscan_kernel<<<1, 256, 0, stream>>>(cnt, bbase, rowstart);
    sort_kernel<<<NBUK, 512, 0, stream>>>(cnt, bbase, binned, rowstart, csr);

    // ---- layer 1 projection ----
    lin1_kernel<<<(N_NODES + 63) / 64, 256, 0, stream>>>(x, W1l, W1r, Y1l, Y1r);

    // ---- fused gather1 + combine + layer-2 projection ----
    gather_lin2<<<N_NODES / 8, 256, 0, stream>>>(rowstart, csr, Y1l, Y1r, b1,
                                                 W2l, W2r, Y2l, Y2r);

    // ---- fused gather2 + combine + output projection ----
    gather_out<<<N_NODES / 8, 256, 0, stream>>>(rowstart, csr, Y2l, Y2r, b2, w,
                                                out);
}